// Round 5
// baseline (171.979 us; speedup 1.0000x reference)
//
#include <hip/hip_runtime.h>
#include <hip/hip_bf16.h>
#include <math.h>

#define SELU_SCALE 1.0507009873554805f
#define SELU_ALPHA 1.6732632423543772f

static constexpr int B_ = 16, T_ = 16, L_ = 512, H_ = 768;

typedef __bf16 bf16x8 __attribute__((ext_vector_type(8)));
typedef __bf16 bf16x4 __attribute__((ext_vector_type(4)));
typedef float  f32x4  __attribute__((ext_vector_type(4)));

__device__ __forceinline__ float bf_lo(unsigned u) { return __uint_as_float(u << 16); }
__device__ __forceinline__ float bf_hi(unsigned u) { return __uint_as_float(u & 0xFFFF0000u); }

__device__ __forceinline__ float selu_core(float x) {
    float e = fmaf(__expf(x), SELU_ALPHA, -SELU_ALPHA);
    return x > 0.0f ? x : e;
}

__device__ __forceinline__ bf16x4 cvt4(float4 f) {
    bf16x4 o;
    o.x = (__bf16)f.x; o.y = (__bf16)f.y; o.z = (__bf16)f.z; o.w = (__bf16)f.w;
    return o;
}

__device__ __forceinline__ int sw3(int r) { return (r ^ (r >> 2)) & 3; }

__device__ __forceinline__ void load16_lds(const __bf16* g, __bf16* l) {
    __builtin_amdgcn_global_load_lds(
        (const __attribute__((address_space(1))) unsigned int*)g,
        (__attribute__((address_space(3))) unsigned int*)l, 16, 0, 0);
}

// ---------------- prep: W1/W2 -> bf16, dj gather -> bf16, zero out --------------
__global__ __launch_bounds__(256) void prep_k(
        const float* __restrict__ w1, const float* __restrict__ w2,
        const float* __restrict__ dec, const int* __restrict__ Yi,
        __bf16* __restrict__ w1b, __bf16* __restrict__ w2b,
        __bf16* __restrict__ djb, float* __restrict__ out) {
    const int NW = H_ * H_ / 4;                // 147456 float4s
    int i = blockIdx.x * 256 + threadIdx.x;
    if (i == 0) out[0] = 0.0f;
    if (i < NW) {
        ((bf16x4*)w1b)[i] = cvt4(((const float4*)w1)[i]);
    } else if (i < 2 * NW) {
        int j = i - NW;
        ((bf16x4*)w2b)[j] = cvt4(((const float4*)w2)[j]);
    } else {
        int j = i - 2 * NW;                    // < 49152
        int bt = j / 192, c = j % 192;
        int b = bt >> 4;
        int y = Yi[bt];
        ((bf16x4*)djb)[bt * 192 + c] = cvt4(((const float4*)dec)[(b * L_ + y) * 192 + c]);
    }
}

// ---------------- WD = dj @ W2^T (small MFMA GEMM) ------------------------------
// grid 96 = 16 b x 6 n-chunks(128). 256 thr. M=16 (one m-tile), BK=32, 24 iters.
__global__ __launch_bounds__(256) void wd_k(
        const __bf16* __restrict__ djb, const __bf16* __restrict__ w2b,
        __bf16* __restrict__ wdb) {
    __shared__ __bf16 Bs[128 * 32];   // 8 KB
    __shared__ __bf16 As[16 * 32];    // 1 KB
    const int b = blockIdx.x / 6, n0 = (blockIdx.x % 6) * 128;
    const int wave = threadIdx.x >> 6, lane = threadIdx.x & 63;
    const int lr = lane & 15, q = lane >> 4;
    const int dr = lane >> 2;
    const int segb = ((lane & 3) ^ sw3(dr)) * 8;
    const __bf16* Bg = w2b + (size_t)(n0 + dr) * 768 + segb;
    const __bf16* Ag = djb + (size_t)(b * 16 + dr) * 768 + segb;
    const int rb0 = (wave * 2) * 16, rb1 = (wave * 2 + 1) * 16;

    const int slot = (q ^ sw3(lr)) * 8;
    const int aoff = lr * 32 + slot;
    const int boff0 = (wave * 32 + lr) * 32 + slot;
    const int boff1 = (wave * 32 + 16 + lr) * 32 + slot;

    f32x4 acc0 = {}, acc1 = {};
    for (int k0 = 0; k0 < 768; k0 += 32) {
        if (wave == 0) load16_lds(Ag + k0, As);
        load16_lds(Bg + (size_t)rb0 * 768 + k0, Bs + rb0 * 32);
        load16_lds(Bg + (size_t)rb1 * 768 + k0, Bs + rb1 * 32);
        __syncthreads();
        bf16x8 a  = *(const bf16x8*)&As[aoff];
        bf16x8 b0 = *(const bf16x8*)&Bs[boff0];
        bf16x8 b1 = *(const bf16x8*)&Bs[boff1];
        acc0 = __builtin_amdgcn_mfma_f32_16x16x32_bf16(a, b0, acc0, 0, 0, 0);
        acc1 = __builtin_amdgcn_mfma_f32_16x16x32_bf16(a, b1, acc1, 0, 0, 0);
        __syncthreads();
    }
#pragma unroll
    for (int r = 0; r < 4; ++r) {
        wdb[(size_t)(b * 16 + q * 4 + r) * 768 + n0 + wave * 32 + lr]      = (__bf16)acc0[r];
        wdb[(size_t)(b * 16 + q * 4 + r) * 768 + n0 + wave * 32 + 16 + lr] = (__bf16)acc1[r];
    }
}

// ---------------- fused WE-GEMM + scores ----------------------------------------
// 256 blocks (b, 32-l chunk), 512 thr (8 waves). GEMM: BM=32, BN=768, BK=32,
// wave-tile 32x96 (2x6 MFMA 16x16x32). A staged from f32 hn inline (read once),
// B = w1b via global_load_lds (L2-resident). WE acc -> LDS bf16 (stride 776,
// 2-way banks = free) -> scores phase per-thread (t,l) in same block.
__global__ __launch_bounds__(512) void wescore_k(
        const float* __restrict__ hn, const __bf16* __restrict__ w1b,
        const __bf16* __restrict__ wdb, const float* __restrict__ V,
        const int* __restrict__ Xi, float* __restrict__ scores) {
    __shared__ __align__(16) char smem[79616];
    __bf16* Bs  = (__bf16*)smem;                 // 768x32 = 48 KB   (GEMM)
    __bf16* WEs = (__bf16*)smem;                 // 32x776 = 48.5 KB (scores; aliases Bs)
    __bf16* As  = (__bf16*)(smem + 49664);       // 32x32  = 2 KB
    __bf16* WDs = (__bf16*)(smem + 51712);       // 16x776 = 24.25 KB
    float*  Vs  = (float*)(smem + 76544);        // 768 f32 = 3 KB

    const int b = blockIdx.x >> 4, l0 = (blockIdx.x & 15) * 32;
    const int tid = threadIdx.x;
    const int wave = tid >> 6, lane = tid & 63;
    const int lr = lane & 15, q = lane >> 4;

    // prologue: stage WD rows (bf16) and V (f32)
    for (int cid = tid; cid < 16 * 96; cid += 512) {
        int r = cid / 96, cc = cid % 96;
        *(uint4*)&WDs[r * 776 + cc * 8] = *(const uint4*)(wdb + (size_t)(b * 16 + r) * 768 + cc * 8);
    }
    if (tid < 192) *(float4*)&Vs[tid * 4] = ((const float4*)V)[tid];

    // B DMA per-lane source map (slot = lane&3 stores global seg (lane&3)^sw3(row))
    const int dr = lane >> 2;
    const int segb = ((lane & 3) ^ sw3(dr)) * 8;
    const __bf16* Bg = w1b + (size_t)dr * 768 + segb;

    // A staging: thread -> (row, 2 k-elems), swizzled bf16x2 LDS write
    const int arow = tid >> 4, apk = tid & 15;
    const float* Ahn = hn + (size_t)(b * 512 + l0 + arow) * 768 + apk * 2;
    unsigned* Aw = (unsigned*)&As[arow * 32 + ((apk >> 2) ^ sw3(arow)) * 8 + (apk & 3) * 2];

    // fragment offsets
    const int slot = (q ^ sw3(lr)) * 8;
    int aoffs[2], boffs[6];
#pragma unroll
    for (int i = 0; i < 2; ++i) aoffs[i] = (i * 16 + lr) * 32 + slot;
#pragma unroll
    for (int j = 0; j < 6; ++j) boffs[j] = (wave * 96 + j * 16 + lr) * 32 + slot;

    f32x4 acc[2][6] = {};

    for (int k0 = 0; k0 < 768; k0 += 32) {
#pragma unroll
        for (int c = 0; c < 6; ++c) {
            int rb = (c * 8 + wave) * 16;
            load16_lds(Bg + (size_t)rb * 768 + k0, Bs + rb * 32);
        }
        float2 av = *(const float2*)(Ahn + k0);
        union { __bf16 h[2]; unsigned u; } pk;
        pk.h[0] = (__bf16)av.x; pk.h[1] = (__bf16)av.y;
        *Aw = pk.u;
        __syncthreads();
        bf16x8 af[2], bfr[6];
#pragma unroll
        for (int i = 0; i < 2; ++i) af[i]  = *(const bf16x8*)&As[aoffs[i]];
#pragma unroll
        for (int j = 0; j < 6; ++j) bfr[j] = *(const bf16x8*)&Bs[boffs[j]];
#pragma unroll
        for (int i = 0; i < 2; ++i)
#pragma unroll
            for (int j = 0; j < 6; ++j)
                acc[i][j] = __builtin_amdgcn_mfma_f32_16x16x32_bf16(af[i], bfr[j], acc[i][j], 0, 0, 0);
        __syncthreads();
    }

    // WE accumulators -> LDS bf16 (Bs region is dead now)
#pragma unroll
    for (int i = 0; i < 2; ++i)
#pragma unroll
        for (int j = 0; j < 6; ++j)
#pragma unroll
            for (int r = 0; r < 4; ++r)
                WEs[(i * 16 + q * 4 + r) * 776 + wave * 96 + j * 16 + lr] = (__bf16)acc[i][j][r];
    __syncthreads();

    // scores phase: thread -> (t = tid>>5, l = l0 + (tid&31))
    const int t = tid >> 5, ls = tid & 31, l = l0 + ls;
    const int X = Xi[b * 16 + t];
    if (__all(l < X)) return;   // whole wave masked (ref masks l < Xindex)

    float a0 = 0.f, a1 = 0.f, a2 = 0.f, a3 = 0.f;
#pragma unroll 4
    for (int h = 0; h < 768; h += 8) {
        uint4 we = *(const uint4*)&WEs[ls * 776 + h];
        uint4 wd = *(const uint4*)&WDs[t * 776 + h];
        float4 v0 = *(const float4*)&Vs[h];
        float4 v1 = *(const float4*)&Vs[h + 4];
        a0 = fmaf(selu_core(bf_lo(we.x) + bf_lo(wd.x)), v0.x, a0);
        a1 = fmaf(selu_core(bf_hi(we.x) + bf_hi(wd.x)), v0.y, a1);
        a2 = fmaf(selu_core(bf_lo(we.y) + bf_lo(wd.y)), v0.z, a2);
        a3 = fmaf(selu_core(bf_hi(we.y) + bf_hi(wd.y)), v0.w, a3);
        a0 = fmaf(selu_core(bf_lo(we.z) + bf_lo(wd.z)), v1.x, a0);
        a1 = fmaf(selu_core(bf_hi(we.z) + bf_hi(wd.z)), v1.y, a1);
        a2 = fmaf(selu_core(bf_lo(we.w) + bf_lo(wd.w)), v1.z, a2);
        a3 = fmaf(selu_core(bf_hi(we.w) + bf_hi(wd.w)), v1.w, a3);
    }
    if (l >= X) {
        float dot = SELU_SCALE * ((a0 + a1) + (a2 + a3));
        float sc  = dot > 0.0f ? SELU_SCALE * dot
                               : SELU_SCALE * SELU_ALPHA * (__expf(dot) - 1.0f);
        scores[(size_t)(b * 16 + t) * 512 + l] = sc;
    }
}

// ---------------- per-(b,t) masked logsumexp + gold + mean (atomic) -------------
__global__ __launch_bounds__(64) void loss_k(
        const float* __restrict__ scores, const int* __restrict__ Xi,
        const int* __restrict__ Yi, float* __restrict__ out) {
    const int bt = blockIdx.x;
    const int lane = threadIdx.x;
    const int X = Xi[bt];
    const int Y = Yi[bt];
    const float* row = scores + (size_t)bt * L_;

    float m = -INFINITY;
    for (int l = X + lane; l < L_; l += 64) m = fmaxf(m, row[l]);
#pragma unroll
    for (int off = 32; off > 0; off >>= 1) m = fmaxf(m, __shfl_xor(m, off));

    float s = 0.0f;
    for (int l = X + lane; l < L_; l += 64) s += __expf(row[l] - m);
#pragma unroll
    for (int off = 32; off > 0; off >>= 1) s += __shfl_xor(s, off);

    if (lane == 0)
        atomicAdd(out, (m + __logf(s) - row[Y]) * (1.0f / (B_ * T_)));
}

// ---------------- launch ----------------
extern "C" void kernel_launch(void* const* d_in, const int* in_sizes, int n_in,
                              void* d_out, int out_size, void* d_ws, size_t ws_size,
                              hipStream_t stream) {
    const float* hn  = (const float*)d_in[0];
    const float* dec = (const float*)d_in[1];
    const float* W1  = (const float*)d_in[2];
    const float* W2  = (const float*)d_in[3];
    const float* V   = (const float*)d_in[4];
    const int*   Xi  = (const int*)d_in[5];
    const int*   Yi  = (const int*)d_in[6];
    float* out = (float*)d_out;

    char* ws = (char*)d_ws;
    size_t off = 0;
    auto alloc = [&](size_t bytes) -> char* {
        char* p = ws + off;
        off += (bytes + 255) & ~(size_t)255;
        return p;
    };
    __bf16* w1b    = (__bf16*)alloc((size_t)H_ * H_ * 2);
    __bf16* w2b    = (__bf16*)alloc((size_t)H_ * H_ * 2);
    __bf16* djb    = (__bf16*)alloc((size_t)B_ * T_ * H_ * 2);
    __bf16* wdb    = (__bf16*)alloc((size_t)B_ * T_ * H_ * 2);
    float*  scores = (float*)alloc((size_t)B_ * T_ * L_ * 4);

    // prep: (2*147456 + 49152) / 256 = 1344 blocks
    prep_k<<<1344, 256, 0, stream>>>(W1, W2, dec, Yi, w1b, w2b, djb, out);
    // WD GEMM: 16 b x 6 n-chunks
    wd_k<<<96, 256, 0, stream>>>(djb, w2b, wdb);
    // fused WE-GEMM + scores: 16 b x 16 l-chunks
    wescore_k<<<256, 512, 0, stream>>>(hn, w1b, wdb, V, Xi, scores);
    loss_k<<<B_ * T_, 64, 0, stream>>>(scores, Xi, Yi, out);
}

// Round 6
// 165.783 us; speedup vs baseline: 1.0374x; 1.0374x over previous
//
#include <hip/hip_runtime.h>
#include <hip/hip_bf16.h>
#include <math.h>

#define SELU_SCALE 1.0507009873554805f
#define SELU_ALPHA 1.6732632423543772f

static constexpr int B_ = 16, T_ = 16, L_ = 512, H_ = 768;

typedef __bf16 bf16x8 __attribute__((ext_vector_type(8)));
typedef __bf16 bf16x4 __attribute__((ext_vector_type(4)));
typedef float  f32x4  __attribute__((ext_vector_type(4)));

__device__ __forceinline__ float bf_lo(unsigned u) { return __uint_as_float(u << 16); }
__device__ __forceinline__ float bf_hi(unsigned u) { return __uint_as_float(u & 0xFFFF0000u); }

__device__ __forceinline__ float selu_core(float x) {
    float e = fmaf(__expf(x), SELU_ALPHA, -SELU_ALPHA);
    return x > 0.0f ? x : e;
}

__device__ __forceinline__ bf16x4 cvt4(float4 f) {
    bf16x4 o;
    o.x = (__bf16)f.x; o.y = (__bf16)f.y; o.z = (__bf16)f.z; o.w = (__bf16)f.w;
    return o;
}

// LDS k-segment slot swizzle: slot = seg ^ ((row>>1)&3). Verified by 8-lane
// phase enumeration: conflict-free for the A/B ds_write_b128 maps and the
// fragment ds_read_b128 map below (each aligned 8-lane group covers all 32
// banks exactly once at row stride 32 bf16 = 16 banks).
__device__ __forceinline__ int xsw(int r) { return (r >> 1) & 3; }

// ---------------- prep: W1/W2 -> bf16, dj gather (f32), zero out ----------------
__global__ __launch_bounds__(256) void prep_k(
        const float* __restrict__ w1, const float* __restrict__ w2,
        const float* __restrict__ dec, const int* __restrict__ Yi,
        __bf16* __restrict__ w1b, __bf16* __restrict__ w2b,
        float* __restrict__ djf, float* __restrict__ out) {
    const int NW = H_ * H_ / 4;                // 147456 float4s
    int i = blockIdx.x * 256 + threadIdx.x;
    if (i == 0) out[0] = 0.0f;
    if (i < NW) {
        ((bf16x4*)w1b)[i] = cvt4(((const float4*)w1)[i]);
    } else if (i < 2 * NW) {
        int j = i - NW;
        ((bf16x4*)w2b)[j] = cvt4(((const float4*)w2)[j]);
    } else {
        int j = i - 2 * NW;                    // < 49152
        int bt = j / 192, c = j % 192;
        int b = bt >> 4;
        int y = Yi[bt];
        ((float4*)djf)[bt * 192 + c] = ((const float4*)dec)[(b * L_ + y) * 192 + c];
    }
}

// ---------------- register-pipelined NT GEMM (WE + WD) --------------------------
// C[m][n] = sum_k A[m][k] * B[n][k]. A f32 (hn/djf, converted in-register),
// B bf16 (w1b/w2b). BM=64, BN=128, BK=32, 256 thr = 4 waves (2x2) of 32x64.
// Pipeline: tile k+1 global->VGPR issued between raw s_barriers so loads stay
// in flight across the barrier (no vmcnt(0) drain -- plain register loads need
// none); VGPR->LDS ds_write_b128 at top of next iteration.
__global__ __launch_bounds__(256) void gemm_k(
        const float* __restrict__ hn, const float* __restrict__ djf,
        const __bf16* __restrict__ w1b, const __bf16* __restrict__ w2b,
        __bf16* __restrict__ web, __bf16* __restrict__ wdb) {
    __shared__ __bf16 As[64 * 32];    // 4 KB
    __shared__ __bf16 Bs[128 * 32];   // 8 KB

    int bx = blockIdx.x;
    const float* Af; const __bf16* Bw; __bf16* C;
    if (bx < 768) { Af = hn; Bw = w1b; C = web; }
    else          { bx -= 768; Af = djf; Bw = w2b; C = wdb; }
    const int m0 = (bx / 6) * 64, n0 = (bx % 6) * 128;

    const int tid = threadIdx.x;
    const int wave = tid >> 6, lane = tid & 63;
    const int wm = (wave >> 1) * 32, wn = (wave & 1) * 64;
    const int lr = lane & 15, q = lane >> 4;

    // A staging: thread -> row tid>>2, k-seg tid&3 (8 f32 -> 8 bf16 = 1 b128)
    const int arow = tid >> 2, aseg = tid & 3;
    const float* Ag = Af + (size_t)(m0 + arow) * 768 + aseg * 8;
    bf16x8* AsW = (bf16x8*)&As[arow * 32 + ((aseg ^ xsw(arow)) * 8)];

    // B staging: thread -> row tid>>1, k-segs (tid&1)*2 and +1 (2 x b128)
    const int brow = tid >> 1, bs0 = (tid & 1) * 2;
    const __bf16* Bg = Bw + (size_t)(n0 + brow) * 768 + bs0 * 8;
    uint4* BsW0 = (uint4*)&Bs[brow * 32 + (((bs0)     ^ xsw(brow)) * 8)];
    uint4* BsW1 = (uint4*)&Bs[brow * 32 + (((bs0 + 1) ^ xsw(brow)) * 8)];

    // fragment read offsets (seg q of row)
    int aoff[2], boff[4];
#pragma unroll
    for (int i = 0; i < 2; ++i) {
        int r = wm + i * 16 + lr;
        aoff[i] = r * 32 + (q ^ xsw(r)) * 8;
    }
#pragma unroll
    for (int j = 0; j < 4; ++j) {
        int r = wn + j * 16 + lr;
        boff[j] = r * 32 + (q ^ xsw(r)) * 8;
    }

    f32x4 acc[2][4] = {};

    // prologue: prefetch tile 0 into registers
    float4 pa0 = *(const float4*)(Ag);
    float4 pa1 = *(const float4*)(Ag + 4);
    uint4  pb0 = *(const uint4*)(Bg);
    uint4  pb1 = *(const uint4*)(Bg + 8);

    for (int k0 = 0; k0 < 768; k0 += 32) {
        // stage registers -> LDS (compiler inserts vmcnt waits on first use)
        bf16x8 aw;
        aw[0] = (__bf16)pa0.x; aw[1] = (__bf16)pa0.y;
        aw[2] = (__bf16)pa0.z; aw[3] = (__bf16)pa0.w;
        aw[4] = (__bf16)pa1.x; aw[5] = (__bf16)pa1.y;
        aw[6] = (__bf16)pa1.z; aw[7] = (__bf16)pa1.w;
        *AsW  = aw;
        *BsW0 = pb0;
        *BsW1 = pb1;
        // writes visible to all waves, then barrier (no vmem drain needed)
        asm volatile("s_waitcnt lgkmcnt(0)\n\ts_barrier" ::: "memory");

        // prefetch tile k+1 -- stays IN FLIGHT across the bottom barrier
        if (k0 + 32 < 768) {
            pa0 = *(const float4*)(Ag + k0 + 32);
            pa1 = *(const float4*)(Ag + k0 + 36);
            pb0 = *(const uint4*)(Bg + k0 + 32);
            pb1 = *(const uint4*)(Bg + k0 + 40);
        }

        bf16x8 af[2], bfr[4];
#pragma unroll
        for (int i = 0; i < 2; ++i) af[i]  = *(const bf16x8*)&As[aoff[i]];
#pragma unroll
        for (int j = 0; j < 4; ++j) bfr[j] = *(const bf16x8*)&Bs[boff[j]];
#pragma unroll
        for (int i = 0; i < 2; ++i)
#pragma unroll
            for (int j = 0; j < 4; ++j)
                acc[i][j] = __builtin_amdgcn_mfma_f32_16x16x32_bf16(af[i], bfr[j], acc[i][j], 0, 0, 0);
        // frag reads already waited (before MFMA use); raw barrier only
        asm volatile("s_barrier" ::: "memory");
    }

#pragma unroll
    for (int i = 0; i < 2; ++i)
#pragma unroll
        for (int j = 0; j < 4; ++j)
#pragma unroll
            for (int r = 0; r < 4; ++r) {
                int row = m0 + wm + i * 16 + q * 4 + r;
                int col = n0 + wn + j * 16 + lr;
                C[(size_t)row * 768 + col] = (__bf16)acc[i][j][r];
            }
}

// ---------------- fused scores: per-lane (t,l), no shuffles ----------------
__global__ __launch_bounds__(256) void scores_k(
        const __bf16* __restrict__ web, const __bf16* __restrict__ wdb,
        const float* __restrict__ V, const int* __restrict__ Xi,
        float* __restrict__ scores) {
    __shared__ float    we_s[16][772];
    __shared__ unsigned wd_s[16][388];
    __shared__ float    v_s[768];

    const int b = blockIdx.x, l0 = blockIdx.y * 16;

    for (int c = threadIdx.x; c < 16 * 96; c += 256) {
        int r = c / 96, cc = c % 96;
        uint4 v = *(const uint4*)(web + ((size_t)(b * L_ + l0 + r)) * H_ + cc * 8);
        float4 f0, f1;
        f0.x = bf_lo(v.x); f0.y = bf_hi(v.x); f0.z = bf_lo(v.y); f0.w = bf_hi(v.y);
        f1.x = bf_lo(v.z); f1.y = bf_hi(v.z); f1.z = bf_lo(v.w); f1.w = bf_hi(v.w);
        *(float4*)&we_s[r][cc * 8]     = f0;
        *(float4*)&we_s[r][cc * 8 + 4] = f1;
    }
    for (int c = threadIdx.x; c < 16 * 96; c += 256) {
        int r = c / 96, cc = c % 96;
        *(uint4*)&wd_s[r][cc * 4] = *(const uint4*)(wdb + ((size_t)(b * T_ + r)) * H_ + cc * 8);
    }
    if (threadIdx.x < 192) *(float4*)&v_s[threadIdx.x * 4] = ((const float4*)V)[threadIdx.x];
    __syncthreads();

    const int t = threadIdx.x >> 4;
    const int ls = threadIdx.x & 15;
    const int l = l0 + ls;
    const int X = Xi[b * T_ + t];
    if (!__any(l >= X)) return;

    float a0 = 0.f, a1 = 0.f, a2 = 0.f, a3 = 0.f;
#pragma unroll 4
    for (int h = 0; h < H_; h += 8) {
        float4 w0 = *(const float4*)&we_s[ls][h];
        float4 w1 = *(const float4*)&we_s[ls][h + 4];
        uint4  wd = *(const uint4*)&wd_s[t][h >> 1];
        float4 v0 = *(const float4*)&v_s[h];
        float4 v1 = *(const float4*)&v_s[h + 4];
        a0 = fmaf(selu_core(w0.x + bf_lo(wd.x)), v0.x, a0);
        a1 = fmaf(selu_core(w0.y + bf_hi(wd.x)), v0.y, a1);
        a2 = fmaf(selu_core(w0.z + bf_lo(wd.y)), v0.z, a2);
        a3 = fmaf(selu_core(w0.w + bf_hi(wd.y)), v0.w, a3);
        a0 = fmaf(selu_core(w1.x + bf_lo(wd.z)), v1.x, a0);
        a1 = fmaf(selu_core(w1.y + bf_hi(wd.z)), v1.y, a1);
        a2 = fmaf(selu_core(w1.z + bf_lo(wd.w)), v1.z, a2);
        a3 = fmaf(selu_core(w1.w + bf_hi(wd.w)), v1.w, a3);
    }
    float dot = SELU_SCALE * ((a0 + a1) + (a2 + a3));
    float sc  = dot > 0.0f ? SELU_SCALE * dot
                           : SELU_SCALE * SELU_ALPHA * (__expf(dot) - 1.0f);
    scores[((size_t)(b * T_ + t)) * L_ + l] = sc;
}

// ---------------- per-(b,t) masked logsumexp + gold + mean (atomic) -------------
__global__ __launch_bounds__(64) void loss_k(
        const float* __restrict__ scores, const int* __restrict__ Xi,
        const int* __restrict__ Yi, float* __restrict__ out) {
    const int bt = blockIdx.x;
    const int lane = threadIdx.x;
    const int X = Xi[bt];
    const int Y = Yi[bt];
    const float* row = scores + (size_t)bt * L_;

    float m = -INFINITY;
    for (int l = X + lane; l < L_; l += 64) m = fmaxf(m, row[l]);
#pragma unroll
    for (int off = 32; off > 0; off >>= 1) m = fmaxf(m, __shfl_xor(m, off));

    float s = 0.0f;
    for (int l = X + lane; l < L_; l += 64) s += __expf(row[l] - m);
#pragma unroll
    for (int off = 32; off > 0; off >>= 1) s += __shfl_xor(s, off);

    if (lane == 0)
        atomicAdd(out, (m + __logf(s) - row[Y]) * (1.0f / (B_ * T_)));
}

// ---------------- launch ----------------
extern "C" void kernel_launch(void* const* d_in, const int* in_sizes, int n_in,
                              void* d_out, int out_size, void* d_ws, size_t ws_size,
                              hipStream_t stream) {
    const float* hn  = (const float*)d_in[0];
    const float* dec = (const float*)d_in[1];
    const float* W1  = (const float*)d_in[2];
    const float* W2  = (const float*)d_in[3];
    const float* V   = (const float*)d_in[4];
    const int*   Xi  = (const int*)d_in[5];
    const int*   Yi  = (const int*)d_in[6];
    float* out = (float*)d_out;

    char* ws = (char*)d_ws;
    size_t off = 0;
    auto alloc = [&](size_t bytes) -> char* {
        char* p = ws + off;
        off += (bytes + 255) & ~(size_t)255;
        return p;
    };
    __bf16* w1b    = (__bf16*)alloc((size_t)H_ * H_ * 2);
    __bf16* w2b    = (__bf16*)alloc((size_t)H_ * H_ * 2);
    float*  djf    = (float*)alloc((size_t)B_ * T_ * H_ * 4);
    __bf16* web    = (__bf16*)alloc((size_t)B_ * L_ * H_ * 2);
    __bf16* wdb    = (__bf16*)alloc((size_t)B_ * T_ * H_ * 2);
    float*  scores = (float*)alloc((size_t)B_ * T_ * L_ * 4);

    // prep: (2*147456 + 49152) / 256 = 1344 blocks
    prep_k<<<1344, 256, 0, stream>>>(W1, W2, dec, Yi, w1b, w2b, djf, out);
    // WE (768 blocks) + WD (24 blocks), register-pipelined
    gemm_k<<<792, 256, 0, stream>>>(hn, djf, w1b, w2b, web, wdb);
    scores_k<<<dim3(B_, L_ / 16), 256, 0, stream>>>(web, wdb, V, Xi, scores);
    loss_k<<<B_ * T_, 64, 0, stream>>>(scores, Xi, Yi, out);
}